// Round 3
// baseline (445.160 us; speedup 1.0000x reference)
//
#include <hip/hip_runtime.h>
#include <hip/hip_bf16.h>
#include <math.h>

#define B_ 4
#define T_ 2048
#define C_ 1024
#define H_ 16
#define D_ 64
#define BT (B_*T_)
#define BH (B_*H_)

typedef __bf16 bf16x8 __attribute__((ext_vector_type(8)));
typedef __bf16 bf16x4 __attribute__((ext_vector_type(4)));
typedef float f32x4 __attribute__((ext_vector_type(4)));
typedef unsigned short u16;
typedef u16 u16x8 __attribute__((ext_vector_type(8)));

// async global->LDS, 16B/lane; LDS dest = wave-uniform base + lane*16
#define GLL(g, l) __builtin_amdgcn_global_load_lds( \
    (const __attribute__((address_space(1))) unsigned int*)(g), \
    (__attribute__((address_space(3))) unsigned int*)(l), 16, 0, 0)

__device__ __forceinline__ u16 f2b(float f) {
    union { float f; unsigned u; } v; v.f = f;
    unsigned r = v.u + 0x7fffu + ((v.u >> 16) & 1u);
    return (u16)(r >> 16);
}

// ---------------- cast fp32 -> bf16 (n divisible by 1024) ----------------
__global__ __launch_bounds__(256) void cast_f32_bf16(const float* __restrict__ in,
                                                     u16* __restrict__ out) {
    int g = blockIdx.x * 256 + threadIdx.x;
    float4 x = ((const float4*)in)[g];
    ushort4 o;
    o.x = f2b(x.x); o.y = f2b(x.y); o.z = f2b(x.z); o.w = f2b(x.w);
    ((ushort4*)out)[g] = o;
}

// ------------- Wq/Wk/Wv [H,C,D] fp32 -> [3,H,D,C] bf16 (= [3072,1024]) ----
__global__ __launch_bounds__(256) void transpose_w(const float* __restrict__ Wq,
                                                   const float* __restrict__ Wk,
                                                   const float* __restrict__ Wv,
                                                   u16* __restrict__ out) {
    __shared__ u16 lds[64][72];
    int cb = blockIdx.x, h = blockIdx.y, w = blockIdx.z;
    const float* W = (w == 0) ? Wq : (w == 1) ? Wk : Wv;
    int tid = threadIdx.x;
    int c0 = cb * 64;
    {
        int col = (tid & 15) * 4;
        for (int cc = 0; cc < 4; ++cc) {
            int r = (tid >> 4) + cc * 16;
            float4 x = *(const float4*)&W[(size_t)(h * C_ + c0 + r) * D_ + col];
            lds[r][col + 0] = f2b(x.x); lds[r][col + 1] = f2b(x.y);
            lds[r][col + 2] = f2b(x.z); lds[r][col + 3] = f2b(x.w);
        }
    }
    __syncthreads();
    {
        int tcol = (tid & 7) * 8;
        for (int cc = 0; cc < 2; ++cc) {
            int d = (tid >> 3) + cc * 32;
            u16x8 t;
            for (int j = 0; j < 8; ++j) t[j] = lds[tcol + j][d];
            *(u16x8*)&out[(((size_t)(w * H_ + h) * D_ + d) * C_) + c0 + tcol] = t;
        }
    }
}

// ------- fused QKV GEMM: x[8192,1024] x wt[3072,1024]^T -> q/k/v [BH,T,D] -------
// 128x128 tile, global_load_lds staging (m97 recipe), 4 waves x 64x64.
__global__ __launch_bounds__(256) void qkv_gemm(const u16* __restrict__ xbf,
                                                const u16* __restrict__ wt,
                                                u16* __restrict__ q, u16* __restrict__ k,
                                                u16* __restrict__ v) {
    __shared__ u16 Al[128][64];
    __shared__ u16 Bl[128][64];
    int mb = blockIdx.x, nb = blockIdx.y;
    int tid = threadIdx.x, wv = tid >> 6, lane = tid & 63, l15 = lane & 15, quad = lane >> 4;
    int rowh = (wv & 1) * 64, colh = (wv >> 1) * 64;
    f32x4 acc[4][4];
    #pragma unroll
    for (int i = 0; i < 4; ++i)
        #pragma unroll
        for (int j = 0; j < 4; ++j) acc[i][j] = (f32x4){0.f, 0.f, 0.f, 0.f};
    int srow = wv * 32 + (lane >> 3);
    int scol = (lane & 7) * 8;
    const u16* agp = &xbf[(size_t)(mb * 128 + srow) * C_ + scol];
    const u16* bgp = &wt[(size_t)(nb * 128 + srow) * C_ + scol];
    for (int k0 = 0; k0 < C_; k0 += 64) {
        #pragma unroll
        for (int j = 0; j < 4; ++j) {
            GLL(agp + (size_t)(j * 8) * C_ + k0, &Al[wv * 32 + j * 8][0]);
            GLL(bgp + (size_t)(j * 8) * C_ + k0, &Bl[wv * 32 + j * 8][0]);
        }
        __syncthreads();
        #pragma unroll
        for (int ks = 0; ks < 2; ++ks) {
            bf16x8 af[4], bf[4];
            #pragma unroll
            for (int mt = 0; mt < 4; ++mt)
                af[mt] = *(const bf16x8*)&Al[rowh + mt * 16 + l15][ks * 32 + quad * 8];
            #pragma unroll
            for (int nt = 0; nt < 4; ++nt)
                bf[nt] = *(const bf16x8*)&Bl[colh + nt * 16 + l15][ks * 32 + quad * 8];
            #pragma unroll
            for (int mt = 0; mt < 4; ++mt)
                #pragma unroll
                for (int nt = 0; nt < 4; ++nt)
                    acc[mt][nt] = __builtin_amdgcn_mfma_f32_16x16x32_bf16(af[mt], bf[nt], acc[mt][nt], 0, 0, 0);
        }
        __syncthreads();
    }
    #pragma unroll
    for (int nt = 0; nt < 4; ++nt) {
        int n0 = nb * 128 + colh + nt * 16;
        int wsel = n0 >> 10, hh = (n0 >> 6) & 15, d0 = n0 & 63;
        u16* op = (wsel == 0) ? q : (wsel == 1) ? k : v;
        #pragma unroll
        for (int mt = 0; mt < 4; ++mt)
            #pragma unroll
            for (int r = 0; r < 4; ++r) {
                int m = mb * 128 + rowh + mt * 16 + quad * 4 + r;
                int bb = m >> 11, tt = m & (T_ - 1);
                op[((size_t)(bb * H_ + hh) * T_ + tt) * D_ + d0 + l15] = f2b(acc[mt][nt][r]);
            }
    }
}

// ---------------- V [BH,T,D] -> Vt [BH,D,T] (bf16) ----------------
__global__ __launch_bounds__(256) void vtrans(const u16* __restrict__ v, u16* __restrict__ vt) {
    __shared__ u16 lds[64][72];
    int tb = blockIdx.x, bh = blockIdx.y;
    int t0 = tb * 64, tid = threadIdx.x;
    int col = (tid & 7) * 8;
    for (int cc = 0; cc < 2; ++cc) {
        int r = (tid >> 3) + cc * 32;
        *(u16x8*)&lds[r][col] = *(const u16x8*)&v[((size_t)bh * T_ + t0 + r) * D_ + col];
    }
    __syncthreads();
    for (int cc = 0; cc < 2; ++cc) {
        int d = (tid >> 3) + cc * 32;
        u16x8 t;
        for (int j = 0; j < 8; ++j) t[j] = lds[col + j][d];
        *(u16x8*)&vt[((size_t)bh * D_ + d) * T_ + t0 + col] = t;
    }
}

// -------- barrier-free flash attention (S^T / O^T form), 16 Q rows/wave ----
// Grid (16, BH): block p covers chunk pair (p, 31-p) of 64 Q rows each ->
// every wave does exactly 33 KV-tile units. 4096 waves = 16/CU.
__global__ __launch_bounds__(256) void attn(const u16* __restrict__ q, const u16* __restrict__ kk,
                                            const u16* __restrict__ vt, u16* __restrict__ att) {
    __shared__ u16 Pl[4][16][72];
    int p = blockIdx.x, bh = blockIdx.y;
    int b = bh >> 4, h = bh & 15;
    int tid = threadIdx.x, wid = tid >> 6, lane = tid & 63, l15 = lane & 15, quad = lane >> 4;
    const float scale2 = 0.04508422f;  // C^-0.5 * log2(e)
    const u16* qbase = q + (size_t)bh * T_ * D_;
    const u16* kbase = kk + (size_t)bh * T_ * D_;
    const u16* vbase = vt + (size_t)bh * D_ * T_;
    u16* pw = &Pl[wid][0][0];
    bf16x8 ones;
    #pragma unroll
    for (int j = 0; j < 8; ++j) ones[j] = (__bf16)1.0f;

    for (int ci = 0; ci < 2; ++ci) {
        int c = ci ? (31 - p) : p;
        int R0 = c * 64 + wid * 16;
        // Q^T B-frags: B[k=d][n=qrow]
        bf16x8 bq[2];
        #pragma unroll
        for (int kd = 0; kd < 2; ++kd)
            bq[kd] = *(const bf16x8*)&qbase[(size_t)(R0 + l15) * D_ + kd * 32 + quad * 8];
        f32x4 o[4];
        f32x4 lacc = (f32x4){0.f, 0.f, 0.f, 0.f};
        float m2 = -INFINITY;
        #pragma unroll
        for (int dt = 0; dt < 4; ++dt) o[dt] = (f32x4){0.f, 0.f, 0.f, 0.f};
        for (int kt = 0; kt <= c; ++kt) {
            int k0 = kt * 64;
            // K A-frags: A[m=kv][k=d]
            bf16x8 ak[4][2];
            #pragma unroll
            for (int kvt = 0; kvt < 4; ++kvt)
                #pragma unroll
                for (int kd = 0; kd < 2; ++kd)
                    ak[kvt][kd] = *(const bf16x8*)&kbase[(size_t)(k0 + kvt * 16 + l15) * D_ + kd * 32 + quad * 8];
            // S^T = K . Q^T : C col = qrow(l15), row = kv(quad*4+r)
            f32x4 s[4];
            #pragma unroll
            for (int kvt = 0; kvt < 4; ++kvt) s[kvt] = (f32x4){0.f, 0.f, 0.f, 0.f};
            #pragma unroll
            for (int kd = 0; kd < 2; ++kd)
                #pragma unroll
                for (int kvt = 0; kvt < 4; ++kvt)
                    s[kvt] = __builtin_amdgcn_mfma_f32_16x16x32_bf16(ak[kvt][kd], bq[kd], s[kvt], 0, 0, 0);
            // V^T A-frags issued now; consumed after softmax (latency hidden)
            bf16x8 av[4][2];
            #pragma unroll
            for (int dt = 0; dt < 4; ++dt)
                #pragma unroll
                for (int ks = 0; ks < 2; ++ks)
                    av[dt][ks] = *(const bf16x8*)&vbase[(size_t)(dt * 16 + l15) * T_ + k0 + ks * 32 + quad * 8];
            if (kt == c) {  // causal mask, diagonal tile only
                int qabs = R0 + l15;
                #pragma unroll
                for (int kvt = 0; kvt < 4; ++kvt) {
                    int kvb = k0 + kvt * 16 + quad * 4;
                    #pragma unroll
                    for (int r = 0; r < 4; ++r)
                        if (kvb + r > qabs) s[kvt][r] = -INFINITY;
                }
            }
            // online softmax (exp2 domain): 16 in-lane fmax + 2 shfl
            float vm = s[0][0];
            #pragma unroll
            for (int kvt = 0; kvt < 4; ++kvt)
                #pragma unroll
                for (int r = 0; r < 4; ++r) vm = fmaxf(vm, s[kvt][r]);
            vm = fmaxf(vm, __shfl_xor(vm, 16));
            vm = fmaxf(vm, __shfl_xor(vm, 32));
            float mn = fmaxf(m2, vm * scale2);
            float alpha = __builtin_amdgcn_exp2f(m2 - mn);
            m2 = mn;
            #pragma unroll
            for (int kvt = 0; kvt < 4; ++kvt)
                #pragma unroll
                for (int r = 0; r < 4; ++r)
                    s[kvt][r] = __builtin_amdgcn_exp2f(fmaf(s[kvt][r], scale2, -m2));
            #pragma unroll
            for (int dt = 0; dt < 4; ++dt)
                #pragma unroll
                for (int r = 0; r < 4; ++r) o[dt][r] *= alpha;
            #pragma unroll
            for (int r = 0; r < 4; ++r) lacc[r] *= alpha;
            // P -> wave-private LDS: P[qrow][kv] (bf16)
            #pragma unroll
            for (int kvt = 0; kvt < 4; ++kvt) {
                bf16x4 w;
                #pragma unroll
                for (int r = 0; r < 4; ++r) w[r] = (__bf16)s[kvt][r];
                *(bf16x4*)&pw[l15 * 72 + kvt * 16 + quad * 4] = w;
            }
            // O^T += V^T . P^T ; l += ones . P^T
            #pragma unroll
            for (int ks = 0; ks < 2; ++ks) {
                bf16x8 bp = *(const bf16x8*)&pw[l15 * 72 + ks * 32 + quad * 8];
                #pragma unroll
                for (int dt = 0; dt < 4; ++dt)
                    o[dt] = __builtin_amdgcn_mfma_f32_16x16x32_bf16(av[dt][ks], bp, o[dt], 0, 0, 0);
                lacc = __builtin_amdgcn_mfma_f32_16x16x32_bf16(ones, bp, lacc, 0, 0, 0);
            }
        }
        // epilogue: O^T[d][qrow] / l -> att[b*T+qrow][h*64+d]
        float rl = __builtin_amdgcn_rcpf(lacc[0]);
        int qabs = R0 + l15;
        #pragma unroll
        for (int dt = 0; dt < 4; ++dt) {
            bf16x4 w;
            #pragma unroll
            for (int r = 0; r < 4; ++r) w[r] = (__bf16)(o[dt][r] * rl);
            *(bf16x4*)&att[(size_t)(b * T_ + qabs) * C_ + h * 64 + dt * 16 + quad * 4] = w;
        }
    }
}

// ------ out proj: att[8192,1024] x wo[1024,1024]^T + bo -> fp32 out -------
__global__ __launch_bounds__(256) void out_gemm(const u16* __restrict__ att,
                                                const u16* __restrict__ wo,
                                                const float* __restrict__ bo,
                                                float* __restrict__ out) {
    __shared__ u16 Al[128][64];
    __shared__ u16 Bl[128][64];
    int mb = blockIdx.x, nb = blockIdx.y;
    int tid = threadIdx.x, wv = tid >> 6, lane = tid & 63, l15 = lane & 15, quad = lane >> 4;
    int rowh = (wv & 1) * 64, colh = (wv >> 1) * 64;
    f32x4 acc[4][4];
    #pragma unroll
    for (int i = 0; i < 4; ++i)
        #pragma unroll
        for (int j = 0; j < 4; ++j) acc[i][j] = (f32x4){0.f, 0.f, 0.f, 0.f};
    int srow = wv * 32 + (lane >> 3);
    int scol = (lane & 7) * 8;
    const u16* agp = &att[(size_t)(mb * 128 + srow) * C_ + scol];
    const u16* bgp = &wo[(size_t)(nb * 128 + srow) * C_ + scol];
    for (int k0 = 0; k0 < C_; k0 += 64) {
        #pragma unroll
        for (int j = 0; j < 4; ++j) {
            GLL(agp + (size_t)(j * 8) * C_ + k0, &Al[wv * 32 + j * 8][0]);
            GLL(bgp + (size_t)(j * 8) * C_ + k0, &Bl[wv * 32 + j * 8][0]);
        }
        __syncthreads();
        #pragma unroll
        for (int ks = 0; ks < 2; ++ks) {
            bf16x8 af[4], bf[4];
            #pragma unroll
            for (int mt = 0; mt < 4; ++mt)
                af[mt] = *(const bf16x8*)&Al[rowh + mt * 16 + l15][ks * 32 + quad * 8];
            #pragma unroll
            for (int nt = 0; nt < 4; ++nt)
                bf[nt] = *(const bf16x8*)&Bl[colh + nt * 16 + l15][ks * 32 + quad * 8];
            #pragma unroll
            for (int mt = 0; mt < 4; ++mt)
                #pragma unroll
                for (int nt = 0; nt < 4; ++nt)
                    acc[mt][nt] = __builtin_amdgcn_mfma_f32_16x16x32_bf16(af[mt], bf[nt], acc[mt][nt], 0, 0, 0);
        }
        __syncthreads();
    }
    #pragma unroll
    for (int nt = 0; nt < 4; ++nt) {
        int n = nb * 128 + colh + nt * 16 + l15;
        float bias = bo[n];
        #pragma unroll
        for (int mt = 0; mt < 4; ++mt)
            #pragma unroll
            for (int r = 0; r < 4; ++r) {
                int m = mb * 128 + rowh + mt * 16 + quad * 4 + r;
                out[(size_t)m * C_ + n] = acc[mt][nt][r] + bias;
            }
    }
}

extern "C" void kernel_launch(void* const* d_in, const int* in_sizes, int n_in,
                              void* d_out, int out_size, void* d_ws, size_t ws_size,
                              hipStream_t stream) {
    const float* x  = (const float*)d_in[0];
    const float* Wq = (const float*)d_in[1];
    const float* Wk = (const float*)d_in[2];
    const float* Wv = (const float*)d_in[3];
    const float* Wo = (const float*)d_in[4];
    const float* bo = (const float*)d_in[5];
    float* out = (float*)d_out;
    char* ws = (char*)d_ws;
    u16* xbf  = (u16*)(ws + (size_t)0);           // 16 MB  x bf16 [8192,1024]
    u16* wt   = (u16*)(ws + ((size_t)16 << 20));  //  6 MB  W qkv [3072,1024] bf16
    u16* wobf = (u16*)(ws + ((size_t)22 << 20));  //  2 MB  Wo bf16 [1024,1024]
    u16* qb   = (u16*)(ws + ((size_t)24 << 20));  // 16 MB  q [BH,T,D]
    u16* kb   = (u16*)(ws + ((size_t)40 << 20));  // 16 MB  k [BH,T,D]
    u16* vb   = (u16*)(ws + ((size_t)56 << 20));  // 16 MB  v [BH,T,D]
    u16* vtb  = (u16*)(ws + ((size_t)72 << 20));  // 16 MB  v^T [BH,D,T]
    u16* attb = (u16*)(ws + ((size_t)88 << 20));  // 16 MB  att out [B*T,C]

    hipLaunchKernelGGL(cast_f32_bf16, dim3(BT * C_ / 1024), dim3(256), 0, stream, x, xbf);
    hipLaunchKernelGGL(cast_f32_bf16, dim3(C_ * C_ / 1024), dim3(256), 0, stream, Wo, wobf);
    hipLaunchKernelGGL(transpose_w, dim3(C_ / 64, H_, 3), dim3(256), 0, stream, Wq, Wk, Wv, wt);
    hipLaunchKernelGGL(qkv_gemm, dim3(BT / 128, 3 * C_ / 128), dim3(256), 0, stream, xbf, wt, qb, kb, vb);
    hipLaunchKernelGGL(vtrans, dim3(T_ / 64, BH), dim3(256), 0, stream, vb, vtb);
    hipLaunchKernelGGL(attn, dim3(16, BH), dim3(256), 0, stream, qb, kb, vtb, attb);
    hipLaunchKernelGGL(out_gemm, dim3(BT / 128, C_ / 128), dim3(256), 0, stream, attb, wobf, bo, out);
}

// Round 4
// 303.417 us; speedup vs baseline: 1.4672x; 1.4672x over previous
//
#include <hip/hip_runtime.h>
#include <hip/hip_bf16.h>
#include <math.h>

#define B_ 4
#define T_ 2048
#define C_ 1024
#define H_ 16
#define D_ 64
#define BT (B_*T_)
#define BH (B_*H_)

typedef __bf16 bf16x8 __attribute__((ext_vector_type(8)));
typedef __bf16 bf16x4 __attribute__((ext_vector_type(4)));
typedef float f32x4 __attribute__((ext_vector_type(4)));
typedef unsigned short u16;
typedef u16 u16x8 __attribute__((ext_vector_type(8)));

// async global->LDS, 16B/lane; LDS dest = wave-uniform base + lane*16
#define GLL(g, l) __builtin_amdgcn_global_load_lds( \
    (const __attribute__((address_space(1))) unsigned int*)(g), \
    (__attribute__((address_space(3))) unsigned int*)(l), 16, 0, 0)

__device__ __forceinline__ u16 f2b(float f) {
    union { float f; unsigned u; } v; v.f = f;
    unsigned r = v.u + 0x7fffu + ((v.u >> 16) & 1u);
    return (u16)(r >> 16);
}

// ---------------- cast fp32 -> bf16 (n divisible by 1024) ----------------
__global__ __launch_bounds__(256) void cast_f32_bf16(const float* __restrict__ in,
                                                     u16* __restrict__ out) {
    int g = blockIdx.x * 256 + threadIdx.x;
    float4 x = ((const float4*)in)[g];
    ushort4 o;
    o.x = f2b(x.x); o.y = f2b(x.y); o.z = f2b(x.z); o.w = f2b(x.w);
    ((ushort4*)out)[g] = o;
}

// ------------- Wq/Wk/Wv [H,C,D] fp32 -> [3,H,D,C] bf16 (= [3072,1024]) ----
__global__ __launch_bounds__(256) void transpose_w(const float* __restrict__ Wq,
                                                   const float* __restrict__ Wk,
                                                   const float* __restrict__ Wv,
                                                   u16* __restrict__ out) {
    __shared__ u16 lds[64][72];
    int cb = blockIdx.x, h = blockIdx.y, w = blockIdx.z;
    const float* W = (w == 0) ? Wq : (w == 1) ? Wk : Wv;
    int tid = threadIdx.x;
    int c0 = cb * 64;
    {
        int col = (tid & 15) * 4;
        for (int cc = 0; cc < 4; ++cc) {
            int r = (tid >> 4) + cc * 16;
            float4 x = *(const float4*)&W[(size_t)(h * C_ + c0 + r) * D_ + col];
            lds[r][col + 0] = f2b(x.x); lds[r][col + 1] = f2b(x.y);
            lds[r][col + 2] = f2b(x.z); lds[r][col + 3] = f2b(x.w);
        }
    }
    __syncthreads();
    {
        int tcol = (tid & 7) * 8;
        for (int cc = 0; cc < 2; ++cc) {
            int d = (tid >> 3) + cc * 32;
            u16x8 t;
            for (int j = 0; j < 8; ++j) t[j] = lds[tcol + j][d];
            *(u16x8*)&out[(((size_t)(w * H_ + h) * D_ + d) * C_) + c0 + tcol] = t;
        }
    }
}

// ------- fused QKV GEMM: x[8192,1024] x wt[3072,1024]^T -> q/k/v [BH,T,D] -------
// 128x128 tile; GLL width-16 staging with XOR column swizzle:
//   LDS[row][cb] holds global colblock (cb ^ (row&7)); reads un-swizzle -> 2-way banks.
__global__ __launch_bounds__(256) void qkv_gemm(const u16* __restrict__ xbf,
                                                const u16* __restrict__ wt,
                                                u16* __restrict__ q, u16* __restrict__ k,
                                                u16* __restrict__ v) {
    __shared__ u16 Al[128][64];
    __shared__ u16 Bl[128][64];
    int mb = blockIdx.x, nb = blockIdx.y;
    int tid = threadIdx.x, wv = tid >> 6, lane = tid & 63, l15 = lane & 15, quad = lane >> 4;
    int rowh = (wv & 1) * 64, colh = (wv >> 1) * 64;
    f32x4 acc[4][4];
    #pragma unroll
    for (int i = 0; i < 4; ++i)
        #pragma unroll
        for (int j = 0; j < 4; ++j) acc[i][j] = (f32x4){0.f, 0.f, 0.f, 0.f};
    int lrow = lane >> 3;                       // 0..7
    int srow = wv * 32 + lrow;
    int scol = (((lane & 7) ^ lrow)) * 8;       // swizzled source column
    const u16* agp = &xbf[(size_t)(mb * 128 + srow) * C_ + scol];
    const u16* bgp = &wt[(size_t)(nb * 128 + srow) * C_ + scol];
    int rsw = l15 & 7;                          // read-side swizzle key
    for (int k0 = 0; k0 < C_; k0 += 64) {
        #pragma unroll
        for (int j = 0; j < 4; ++j) {
            GLL(agp + (size_t)(j * 8) * C_ + k0, &Al[wv * 32 + j * 8][0]);
            GLL(bgp + (size_t)(j * 8) * C_ + k0, &Bl[wv * 32 + j * 8][0]);
        }
        __syncthreads();
        #pragma unroll
        for (int ks = 0; ks < 2; ++ks) {
            int cbl = (((ks << 2) | quad) ^ rsw) * 8;
            bf16x8 af[4], bf[4];
            #pragma unroll
            for (int mt = 0; mt < 4; ++mt)
                af[mt] = *(const bf16x8*)&Al[rowh + mt * 16 + l15][cbl];
            #pragma unroll
            for (int nt = 0; nt < 4; ++nt)
                bf[nt] = *(const bf16x8*)&Bl[colh + nt * 16 + l15][cbl];
            #pragma unroll
            for (int mt = 0; mt < 4; ++mt)
                #pragma unroll
                for (int nt = 0; nt < 4; ++nt)
                    acc[mt][nt] = __builtin_amdgcn_mfma_f32_16x16x32_bf16(af[mt], bf[nt], acc[mt][nt], 0, 0, 0);
        }
        __syncthreads();
    }
    #pragma unroll
    for (int nt = 0; nt < 4; ++nt) {
        int n0 = nb * 128 + colh + nt * 16;
        int wsel = n0 >> 10, hh = (n0 >> 6) & 15, d0 = n0 & 63;
        u16* op = (wsel == 0) ? q : (wsel == 1) ? k : v;
        #pragma unroll
        for (int mt = 0; mt < 4; ++mt)
            #pragma unroll
            for (int r = 0; r < 4; ++r) {
                int m = mb * 128 + rowh + mt * 16 + quad * 4 + r;
                int bb = m >> 11, tt = m & (T_ - 1);
                op[((size_t)(bb * H_ + hh) * T_ + tt) * D_ + d0 + l15] = f2b(acc[mt][nt][r]);
            }
    }
}

// ---------------- V [BH,T,D] -> Vt [BH,D,T] (bf16) ----------------
__global__ __launch_bounds__(256) void vtrans(const u16* __restrict__ v, u16* __restrict__ vt) {
    __shared__ u16 lds[64][72];
    int tb = blockIdx.x, bh = blockIdx.y;
    int t0 = tb * 64, tid = threadIdx.x;
    int col = (tid & 7) * 8;
    for (int cc = 0; cc < 2; ++cc) {
        int r = (tid >> 3) + cc * 32;
        *(u16x8*)&lds[r][col] = *(const u16x8*)&v[((size_t)bh * T_ + t0 + r) * D_ + col];
    }
    __syncthreads();
    for (int cc = 0; cc < 2; ++cc) {
        int d = (tid >> 3) + cc * 32;
        u16x8 t;
        for (int j = 0; j < 8; ++j) t[j] = lds[col + j][d];
        *(u16x8*)&vt[((size_t)bh * D_ + d) * T_ + t0 + col] = t;
    }
}

// -------- barrier-free flash attention (S^T / O^T form), 32 Q rows/wave ----
// R2 structure + K-fragment software pipeline (next tile's K issued at top of
// current tile) + V issued under the softmax chain. Zero __syncthreads.
__global__ __launch_bounds__(256, 2) void attn(const u16* __restrict__ q, const u16* __restrict__ kk,
                                               const u16* __restrict__ vt, u16* __restrict__ att) {
    __shared__ u16 Pl[4][32][72];
    int p = blockIdx.x, bh = blockIdx.y;
    int b = bh >> 4, h = bh & 15;
    int tid = threadIdx.x, wid = tid >> 6, lane = tid & 63, l15 = lane & 15, quad = lane >> 4;
    const float scale2 = 0.04508422f;  // C^-0.5 * log2(e)
    const u16* qbase = q + (size_t)bh * T_ * D_;
    const u16* kbase = kk + (size_t)bh * T_ * D_;
    const u16* vbase = vt + (size_t)bh * D_ * T_;
    u16* pw = &Pl[wid][0][0];
    bf16x8 ones;
    #pragma unroll
    for (int j = 0; j < 8; ++j) ones[j] = (__bf16)1.0f;

    for (int ci = 0; ci < 2; ++ci) {
        int c = ci ? (15 - p) : p;
        int R0 = c * 128 + wid * 32;
        // Q^T B-frags: B[k=d][n=qrow]
        bf16x8 bq[2][2];
        #pragma unroll
        for (int qt = 0; qt < 2; ++qt)
            #pragma unroll
            for (int kd = 0; kd < 2; ++kd)
                bq[qt][kd] = *(const bf16x8*)&qbase[(size_t)(R0 + qt * 16 + l15) * D_ + kd * 32 + quad * 8];
        f32x4 o[4][2];
        f32x4 lacc[2];
        float m2[2] = {-INFINITY, -INFINITY};
        #pragma unroll
        for (int dt = 0; dt < 4; ++dt)
            #pragma unroll
            for (int qt = 0; qt < 2; ++qt) o[dt][qt] = (f32x4){0.f, 0.f, 0.f, 0.f};
        lacc[0] = (f32x4){0.f, 0.f, 0.f, 0.f};
        lacc[1] = (f32x4){0.f, 0.f, 0.f, 0.f};
        int ktmax = R0 >> 6;
        // prefetch K-frags for tile 0
        bf16x8 akn[4][2];
        #pragma unroll
        for (int kvt = 0; kvt < 4; ++kvt)
            #pragma unroll
            for (int kd = 0; kd < 2; ++kd)
                akn[kvt][kd] = *(const bf16x8*)&kbase[(size_t)(kvt * 16 + l15) * D_ + kd * 32 + quad * 8];
        for (int kt = 0; kt <= ktmax; ++kt) {
            int k0 = kt * 64;
            bf16x8 ak[4][2];
            #pragma unroll
            for (int kvt = 0; kvt < 4; ++kvt)
                #pragma unroll
                for (int kd = 0; kd < 2; ++kd) ak[kvt][kd] = akn[kvt][kd];
            if (kt < ktmax) {  // issue next tile's K now; latency hides under this tile
                int kn = k0 + 64;
                #pragma unroll
                for (int kvt = 0; kvt < 4; ++kvt)
                    #pragma unroll
                    for (int kd = 0; kd < 2; ++kd)
                        akn[kvt][kd] = *(const bf16x8*)&kbase[(size_t)(kn + kvt * 16 + l15) * D_ + kd * 32 + quad * 8];
            }
            // S^T = K . Q^T : C col = qrow(l15), row = kv(quad*4+r)
            f32x4 s[4][2];
            #pragma unroll
            for (int kvt = 0; kvt < 4; ++kvt)
                #pragma unroll
                for (int qt = 0; qt < 2; ++qt) s[kvt][qt] = (f32x4){0.f, 0.f, 0.f, 0.f};
            #pragma unroll
            for (int kd = 0; kd < 2; ++kd)
                #pragma unroll
                for (int kvt = 0; kvt < 4; ++kvt)
                    #pragma unroll
                    for (int qt = 0; qt < 2; ++qt)
                        s[kvt][qt] = __builtin_amdgcn_mfma_f32_16x16x32_bf16(ak[kvt][kd], bq[qt][kd], s[kvt][qt], 0, 0, 0);
            // V^T A-frags: issued here, consumed after softmax (latency hidden)
            bf16x8 av[4][2];
            #pragma unroll
            for (int dt = 0; dt < 4; ++dt)
                #pragma unroll
                for (int ks = 0; ks < 2; ++ks)
                    av[dt][ks] = *(const bf16x8*)&vbase[(size_t)(dt * 16 + l15) * T_ + k0 + ks * 32 + quad * 8];
            if (kt == ktmax) {  // causal mask, diagonal tile only
                #pragma unroll
                for (int qt = 0; qt < 2; ++qt) {
                    int qabs = R0 + qt * 16 + l15;
                    #pragma unroll
                    for (int kvt = 0; kvt < 4; ++kvt) {
                        int kvb = k0 + kvt * 16 + quad * 4;
                        #pragma unroll
                        for (int r = 0; r < 4; ++r)
                            if (kvb + r > qabs) s[kvt][qt][r] = -INFINITY;
                    }
                }
            }
            // online softmax (exp2 domain): 16 in-lane fmax + 2 shfl per qt
            float alpha[2];
            #pragma unroll
            for (int qt = 0; qt < 2; ++qt) {
                float vm = s[0][qt][0];
                #pragma unroll
                for (int kvt = 0; kvt < 4; ++kvt)
                    #pragma unroll
                    for (int r = 0; r < 4; ++r) vm = fmaxf(vm, s[kvt][qt][r]);
                vm = fmaxf(vm, __shfl_xor(vm, 16));
                vm = fmaxf(vm, __shfl_xor(vm, 32));
                float mn = fmaxf(m2[qt], vm * scale2);
                alpha[qt] = __builtin_amdgcn_exp2f(m2[qt] - mn);
                m2[qt] = mn;
            }
            #pragma unroll
            for (int kvt = 0; kvt < 4; ++kvt)
                #pragma unroll
                for (int qt = 0; qt < 2; ++qt)
                    #pragma unroll
                    for (int r = 0; r < 4; ++r)
                        s[kvt][qt][r] = __builtin_amdgcn_exp2f(fmaf(s[kvt][qt][r], scale2, -m2[qt]));
            #pragma unroll
            for (int dt = 0; dt < 4; ++dt)
                #pragma unroll
                for (int qt = 0; qt < 2; ++qt)
                    #pragma unroll
                    for (int r = 0; r < 4; ++r) o[dt][qt][r] *= alpha[qt];
            #pragma unroll
            for (int qt = 0; qt < 2; ++qt)
                #pragma unroll
                for (int r = 0; r < 4; ++r) lacc[qt][r] *= alpha[qt];
            // P -> wave-private LDS: P[qrow][kv] (bf16)
            #pragma unroll
            for (int qt = 0; qt < 2; ++qt)
                #pragma unroll
                for (int kvt = 0; kvt < 4; ++kvt) {
                    bf16x4 w;
                    #pragma unroll
                    for (int r = 0; r < 4; ++r) w[r] = (__bf16)s[kvt][qt][r];
                    *(bf16x4*)&pw[(qt * 16 + l15) * 72 + kvt * 16 + quad * 4] = w;
                }
            // O^T += V^T . P^T ; l += ones . P^T
            #pragma unroll
            for (int qt = 0; qt < 2; ++qt)
                #pragma unroll
                for (int ks = 0; ks < 2; ++ks) {
                    bf16x8 bp = *(const bf16x8*)&pw[(qt * 16 + l15) * 72 + ks * 32 + quad * 8];
                    #pragma unroll
                    for (int dt = 0; dt < 4; ++dt)
                        o[dt][qt] = __builtin_amdgcn_mfma_f32_16x16x32_bf16(av[dt][ks], bp, o[dt][qt], 0, 0, 0);
                    lacc[qt] = __builtin_amdgcn_mfma_f32_16x16x32_bf16(ones, bp, lacc[qt], 0, 0, 0);
                }
        }
        // epilogue: O^T[d][qrow] / l -> att[b*T+qrow][h*64+d]
        #pragma unroll
        for (int qt = 0; qt < 2; ++qt) {
            float rl = __builtin_amdgcn_rcpf(lacc[qt][0]);
            int qabs = R0 + qt * 16 + l15;
            #pragma unroll
            for (int dt = 0; dt < 4; ++dt) {
                bf16x4 w;
                #pragma unroll
                for (int r = 0; r < 4; ++r) w[r] = (__bf16)(o[dt][qt][r] * rl);
                *(bf16x4*)&att[(size_t)(b * T_ + qabs) * C_ + h * 64 + dt * 16 + quad * 4] = w;
            }
        }
    }
}

// ------ out proj: att[8192,1024] x wo[1024,1024]^T + bo -> fp32 out -------
__global__ __launch_bounds__(256) void out_gemm(const u16* __restrict__ att,
                                                const u16* __restrict__ wo,
                                                const float* __restrict__ bo,
                                                float* __restrict__ out) {
    __shared__ u16 Al[128][64];
    __shared__ u16 Bl[128][64];
    int mb = blockIdx.x, nb = blockIdx.y;
    int tid = threadIdx.x, wv = tid >> 6, lane = tid & 63, l15 = lane & 15, quad = lane >> 4;
    int rowh = (wv & 1) * 64, colh = (wv >> 1) * 64;
    f32x4 acc[4][4];
    #pragma unroll
    for (int i = 0; i < 4; ++i)
        #pragma unroll
        for (int j = 0; j < 4; ++j) acc[i][j] = (f32x4){0.f, 0.f, 0.f, 0.f};
    int lrow = lane >> 3;
    int srow = wv * 32 + lrow;
    int scol = (((lane & 7) ^ lrow)) * 8;
    const u16* agp = &att[(size_t)(mb * 128 + srow) * C_ + scol];
    const u16* bgp = &wo[(size_t)(nb * 128 + srow) * C_ + scol];
    int rsw = l15 & 7;
    for (int k0 = 0; k0 < C_; k0 += 64) {
        #pragma unroll
        for (int j = 0; j < 4; ++j) {
            GLL(agp + (size_t)(j * 8) * C_ + k0, &Al[wv * 32 + j * 8][0]);
            GLL(bgp + (size_t)(j * 8) * C_ + k0, &Bl[wv * 32 + j * 8][0]);
        }
        __syncthreads();
        #pragma unroll
        for (int ks = 0; ks < 2; ++ks) {
            int cbl = (((ks << 2) | quad) ^ rsw) * 8;
            bf16x8 af[4], bf[4];
            #pragma unroll
            for (int mt = 0; mt < 4; ++mt)
                af[mt] = *(const bf16x8*)&Al[rowh + mt * 16 + l15][cbl];
            #pragma unroll
            for (int nt = 0; nt < 4; ++nt)
                bf[nt] = *(const bf16x8*)&Bl[colh + nt * 16 + l15][cbl];
            #pragma unroll
            for (int mt = 0; mt < 4; ++mt)
                #pragma unroll
                for (int nt = 0; nt < 4; ++nt)
                    acc[mt][nt] = __builtin_amdgcn_mfma_f32_16x16x32_bf16(af[mt], bf[nt], acc[mt][nt], 0, 0, 0);
        }
        __syncthreads();
    }
    #pragma unroll
    for (int nt = 0; nt < 4; ++nt) {
        int n = nb * 128 + colh + nt * 16 + l15;
        float bias = bo[n];
        #pragma unroll
        for (int mt = 0; mt < 4; ++mt)
            #pragma unroll
            for (int r = 0; r < 4; ++r) {
                int m = mb * 128 + rowh + mt * 16 + quad * 4 + r;
                out[(size_t)m * C_ + n] = acc[mt][nt][r] + bias;
            }
    }
}

extern "C" void kernel_launch(void* const* d_in, const int* in_sizes, int n_in,
                              void* d_out, int out_size, void* d_ws, size_t ws_size,
                              hipStream_t stream) {
    const float* x  = (const float*)d_in[0];
    const float* Wq = (const float*)d_in[1];
    const float* Wk = (const float*)d_in[2];
    const float* Wv = (const float*)d_in[3];
    const float* Wo = (const float*)d_in[4];
    const float* bo = (const float*)d_in[5];
    float* out = (float*)d_out;
    char* ws = (char*)d_ws;
    u16* xbf  = (u16*)(ws + (size_t)0);           // 16 MB  x bf16 [8192,1024]
    u16* wt   = (u16*)(ws + ((size_t)16 << 20));  //  6 MB  W qkv [3072,1024] bf16
    u16* wobf = (u16*)(ws + ((size_t)22 << 20));  //  2 MB  Wo bf16 [1024,1024]
    u16* qb   = (u16*)(ws + ((size_t)24 << 20));  // 16 MB  q [BH,T,D]
    u16* kb   = (u16*)(ws + ((size_t)40 << 20));  // 16 MB  k [BH,T,D]
    u16* vb   = (u16*)(ws + ((size_t)56 << 20));  // 16 MB  v [BH,T,D]
    u16* vtb  = (u16*)(ws + ((size_t)72 << 20));  // 16 MB  v^T [BH,D,T]
    u16* attb = (u16*)(ws + ((size_t)88 << 20));  // 16 MB  att out [B*T,C]

    hipLaunchKernelGGL(cast_f32_bf16, dim3(BT * C_ / 1024), dim3(256), 0, stream, x, xbf);
    hipLaunchKernelGGL(cast_f32_bf16, dim3(C_ * C_ / 1024), dim3(256), 0, stream, Wo, wobf);
    hipLaunchKernelGGL(transpose_w, dim3(C_ / 64, H_, 3), dim3(256), 0, stream, Wq, Wk, Wv, wt);
    hipLaunchKernelGGL(qkv_gemm, dim3(BT / 128, 3 * C_ / 128), dim3(256), 0, stream, xbf, wt, qb, kb, vb);
    hipLaunchKernelGGL(vtrans, dim3(T_ / 64, BH), dim3(256), 0, stream, vb, vtb);
    hipLaunchKernelGGL(attn, dim3(8, BH), dim3(256), 0, stream, qb, kb, vtb, attb);
    hipLaunchKernelGGL(out_gemm, dim3(BT / 128, C_ / 128), dim3(256), 0, stream, attb, wobf, bo, out);
}